// Round 16
// baseline (64.599 us; speedup 1.0000x reference)
//
#include <hip/hip_runtime.h>

#define NS 2048
#define NP 64
#define ND 80
#define STILE 128
#define NTILE 16            // NS/STILE
#define NTHREADS 512
#define LOG2E 1.4426950408889634f

typedef __attribute__((ext_vector_type(4))) float f32x4;
typedef __attribute__((ext_vector_type(2))) __fp16 fp16x2;
typedef __attribute__((ext_vector_type(8))) _Float16 f16x8;
typedef __attribute__((ext_vector_type(4))) unsigned short u16x4;
typedef unsigned short u16;

// ---- 2 blocks per batch (p-halves), 2 blocks/CU for barrier desync ----
// LDS layout (bytes):
// ehP  u16[2][8][6][264] @ 0     (50688)  f16 enc, 16x16 [s][d] row-major regions
//        region(q,n), q=s>>4, n=d-block (n=5 = K-pad, zeroed once);
//        region stride 264 u16 (528B); per-buf stride 12672 u16.
// mbias f32[2048] @ 50688 (8192); mst f32[4][32] @ 58880; lst @ 59904; modep @ 60928
// prologue overlay: W f32[80][84]@0 ; dec f32[32][84]@26880 ; qtmp f32[32][100]@0
// epilogue overlay: cacc f32[32][84]@0
// SMEM 60944 -> ~62KB block; 2 blocks/CU fit (<=160KB), 16 waves/CU = 4/SIMD.
#define SMEM_BYTES 60944

__device__ __forceinline__ float E2(float x) { return __builtin_amdgcn_exp2f(x); }
__device__ __forceinline__ unsigned pkh(float lo, float hi) {
  union { fp16x2 h; unsigned u; } cv;
  cv.h = __builtin_amdgcn_cvt_pkrtz(lo, hi);
  return cv.u;
}
// 16x16 K=32 f16 MFMA. C/D: col=lane&15, row=4*(lane>>4)+r.
// A/B share the (lane-group g, slot j) -> k=8g+j map (verified R2-R15).
__device__ __forceinline__ f32x4 mfma16f(f16x8 a, f16x8 b, f32x4 c) {
  return __builtin_amdgcn_mfma_f32_16x16x32_f16(a, b, c, 0, 0, 0);
}

__global__ __launch_bounds__(NTHREADS, 4)
void DecoderAttention_62989990363717_kernel(const float* __restrict__ enc,
                                            const float* __restrict__ dec,
                                            const int* __restrict__ maskp,
                                            const float* __restrict__ W,
                                            float* __restrict__ out)
{
  __shared__ __align__(16) char smem[SMEM_BYTES];

  u16* ehP    = (u16*)smem;               // [2][12672]
  float* mbias = (float*)(smem + 50688);  // [2048]
  float* mst  = (float*)(smem + 58880);   // [4][32]
  float* lst  = (float*)(smem + 59904);   // [4][32]
  int* modep  = (int*)(smem + 60928);

  const int tid  = (int)threadIdx.x;
  const int lane = tid & 63;
  const int wv   = tid >> 6;    // 0..7
  const int pp   = wv & 1;      // p-block within this block's 32-p half
  const int sq   = wv >> 1;     // 0..3: 32-row s-slice (quarters {2sq, 2sq+1})
  const int l15  = lane & 15;
  const int g    = lane >> 4;
  const int bb   = (int)blockIdx.x >> 1;   // batch
  const int phB  = (int)blockIdx.x & 1;    // p-half: rows [32*phB, 32*phB+32)

  const float* encB = enc + (size_t)bb * NS * ND;
  const float* decB = dec + ((size_t)bb * NP + 32 * phB) * ND;

  // ---------- prologue: W, dec(scaled) -> LDS; mask->bias; Q ----------
  {
    float* Wl = (float*)smem;            // [80][84]
    float* dl = (float*)(smem + 26880);  // [32][84]
    for (int i = tid; i < 80 * 80; i += NTHREADS) Wl[(i / 80) * 84 + (i % 80)] = W[i];
    for (int i = tid; i < 32 * 80; i += NTHREADS)
      dl[(i / 80) * 84 + (i % 80)] = decB[i] * LOG2E;   // exp2-domain scores
    if (tid == 0) {
      const unsigned* mw = (const unsigned*)maskp;
      int ok = 1;
      for (int i = 0; i < 16; ++i) ok &= (mw[i] <= 1u);
      *modep = ok;   // 1 => int32 mask, 0 => int8 mask
    }
    __syncthreads();
    const int m32 = *modep;
    if (m32) {
#pragma unroll
      for (int k = 0; k < 4; ++k) {
        int v = maskp[(size_t)bb * NS + tid + 512 * k];
        mbias[tid + 512 * k] = v ? -3.0e38f : 0.0f;
      }
    } else {
      unsigned w = ((const unsigned*)maskp)[(size_t)bb * (NS / 4) + tid];
      f32x4 bv;
      bv[0] = (w & 255u)         ? -3.0e38f : 0.0f;
      bv[1] = ((w >> 8) & 255u)  ? -3.0e38f : 0.0f;
      bv[2] = ((w >> 16) & 255u) ? -3.0e38f : 0.0f;
      bv[3] = (w >> 24)          ? -3.0e38f : 0.0f;
      *(f32x4*)&mbias[4 * tid] = bv;
    }
    // Q = dec_half @ W^T in fp32: p = tid>>4 (0..31), e-range = 5*(tid&15)
    float qa[5];
    const int qp = tid >> 4, qw = tid & 15;
#pragma unroll
    for (int j = 0; j < 5; ++j) qa[j] = 0.f;
    for (int kg = 0; kg < 20; ++kg) {
      f32x4 dv = *(const f32x4*)&dl[qp * 84 + kg * 4];
#pragma unroll
      for (int j = 0; j < 5; ++j) {
        f32x4 wv4 = *(const f32x4*)&Wl[(qw * 5 + j) * 84 + kg * 4];
        qa[j] = fmaf(dv.x, wv4.x, qa[j]);
        qa[j] = fmaf(dv.y, wv4.y, qa[j]);
        qa[j] = fmaf(dv.z, wv4.z, qa[j]);
        qa[j] = fmaf(dv.w, wv4.w, qa[j]);
      }
    }
    __syncthreads();            // Wl/dl reads done
    float* qtmp = (float*)smem; // [32][100], zeros at d=80..95
#pragma unroll
    for (int j = 0; j < 5; ++j) qtmp[qp * 100 + qw * 5 + j] = qa[j];
    if (qw == 15) {
#pragma unroll
      for (int z = 0; z < 16; ++z) qtmp[qp * 100 + 80 + z] = 0.f;
    }
    __syncthreads();
  }

  // ---------- Q fragments (persistent, single f16 RNE) ----------
  f16x8 qb[3];
  {
    const float* qtmp = (const float*)smem;
    const int prow = 16 * pp + l15;   // 0..31
#pragma unroll
    for (int kk = 0; kk < 3; ++kk) {
      const int d0 = kk * 32 + g * 8;
      f32x4 f0 = *(const f32x4*)&qtmp[prow * 100 + d0];
      f32x4 f1 = *(const f32x4*)&qtmp[prow * 100 + d0 + 4];
      union { _Float16 h[8]; f16x8 v; } H;
      H.h[0] = (_Float16)f0.x; H.h[1] = (_Float16)f0.y;
      H.h[2] = (_Float16)f0.z; H.h[3] = (_Float16)f0.w;
      H.h[4] = (_Float16)f1.x; H.h[5] = (_Float16)f1.y;
      H.h[6] = (_Float16)f1.z; H.h[7] = (_Float16)f1.w;
      qb[kk] = H.v;
    }
  }
  __syncthreads();   // qtmp dead; staging may overwrite

  // ---------- zero K-pad regions (n=5) once: both buffers, 8 quarters ----------
  if (tid < 256) {
    const int buf = tid >> 7, q = (tid >> 4) & 7, row = tid & 15;
    u16* p = ehP + buf * 12672 + (q * 6 + 5) * 264 + row * 16;
    *(uint4*)p = make_uint4(0u, 0u, 0u, 0u);
    *(uint4*)(p + 8) = make_uint4(0u, 0u, 0u, 0u);
  }

  // loaders: 640 chunks (row, c) of 16 f32; thread tid owns chunk tid,
  // and threads <128 also own chunk 512+tid.
  const int rowA = tid / 5, cA = tid - rowA * 5;
  u16* ePWa = ehP + ((rowA >> 4) * 6 + cA) * 264 + (rowA & 15) * 16;
  const float* gsrcA = encB + rowA * ND + 16 * cA;
  const bool ldrB = (tid < 128);
  const int chB = 512 + tid, rowB = chB / 5, cB = chB - rowB * 5;
  u16* ePWb = ehP + ((rowB >> 4) * 6 + cB) * 264 + (rowB & 15) * 16;
  const float* gsrcB = encB + rowB * ND + 16 * cB;

#define PACK16(dst, q0, q1, q2, q3)                                              \
  do {                                                                           \
    unsigned hh[8];                                                              \
    hh[0] = pkh(q0.x, q0.y); hh[1] = pkh(q0.z, q0.w);                            \
    hh[2] = pkh(q1.x, q1.y); hh[3] = pkh(q1.z, q1.w);                            \
    hh[4] = pkh(q2.x, q2.y); hh[5] = pkh(q2.z, q2.w);                            \
    hh[6] = pkh(q3.x, q3.y); hh[7] = pkh(q3.z, q3.w);                            \
    *(uint4*)(dst)       = make_uint4(hh[0], hh[1], hh[2], hh[3]);               \
    *(uint4*)((dst) + 8) = make_uint4(hh[4], hh[5], hh[6], hh[7]);               \
  } while (0)

#define STAGE_WRITE(bi)                                                          \
  do {                                                                           \
    PACK16(ePWa + (bi) * 12672, rA0, rA1, rA2, rA3);                             \
    if (ldrB) { PACK16(ePWb + (bi) * 12672, rB0, rB1, rB2, rB3); }               \
  } while (0)

  // ---------- stage tile 0 ----------
  {
    f32x4 rA0 = *(const f32x4*)gsrcA,       rA1 = *(const f32x4*)(gsrcA + 4);
    f32x4 rA2 = *(const f32x4*)(gsrcA + 8), rA3 = *(const f32x4*)(gsrcA + 12);
    f32x4 rB0, rB1, rB2, rB3;
    if (ldrB) {
      rB0 = *(const f32x4*)gsrcB;       rB1 = *(const f32x4*)(gsrcB + 4);
      rB2 = *(const f32x4*)(gsrcB + 8); rB3 = *(const f32x4*)(gsrcB + 12);
    }
    STAGE_WRITE(0);
    __syncthreads();
  }

  // ---------- main loop ----------
  f32x4 ctx[5];
#pragma unroll
  for (int n = 0; n < 5; ++n) ctx[n] = (f32x4){0.f, 0.f, 0.f, 0.f};
  // mr init -1e30: masked rows (sv=-3e38) underflow to 0 in all orders.
  float mr = -1.0e30f, lr = 0.f;

  // QK A-frag base (u16): region(2sq+blk, (g>>1)+2kk) + 16*l15 + 8*(g&1)
  const int qkOff = (2 * sq) * 1584 + (g >> 1) * 264 + 16 * l15 + 8 * (g & 1);
  // PV tr-read base (bytes): region(2sq, n) + 8*lane; blk1 = +3168B, n-step = 528B
  const unsigned trBase = (unsigned)(uintptr_t)ehP + (unsigned)(sq * 6336 + 8 * lane);

  for (int tt = 0; tt < NTILE; ++tt) {
    const int cur = tt & 1, nxt = cur ^ 1;
    const bool hn = (tt + 1 < NTILE);
    f32x4 rA0, rA1, rA2, rA3, rB0, rB1, rB2, rB3;
    if (hn) {   // issue next-tile loads early (consumed at STAGE_WRITE)
      const float* sA = gsrcA + (size_t)(tt + 1) * STILE * ND;
      rA0 = *(const f32x4*)sA;       rA1 = *(const f32x4*)(sA + 4);
      rA2 = *(const f32x4*)(sA + 8); rA3 = *(const f32x4*)(sA + 12);
      if (ldrB) {
        const float* sB = gsrcB + (size_t)(tt + 1) * STILE * ND;
        rB0 = *(const f32x4*)sB;       rB1 = *(const f32x4*)(sB + 4);
        rB2 = *(const f32x4*)(sB + 8); rB3 = *(const f32x4*)(sB + 12);
      }
    }

    // ---- QK^T (swapped): two 16-row blocks, K=96, single-f16 Q ----
    f32x4 a0 = (f32x4){0.f, 0.f, 0.f, 0.f}, a1 = (f32x4){0.f, 0.f, 0.f, 0.f};
    {
      const u16* baseH0 = ehP + cur * 12672 + qkOff;
      const u16* baseH1 = baseH0 + 1584;
      f16x8 e0[3], e1[3];
#pragma unroll
      for (int kk = 0; kk < 3; ++kk) {
        e0[kk] = *(const f16x8*)(const void*)(baseH0 + kk * 528);
        e1[kk] = *(const f16x8*)(const void*)(baseH1 + kk * 528);
      }
#pragma unroll
      for (int kk = 0; kk < 3; ++kk) {
        a0 = mfma16f(e0[kk], qb[kk], a0);
        a1 = mfma16f(e1[kk], qb[kk], a1);
      }
    }

    // ---- masked online softmax over 32 rows (exp2 domain), defer-max ----
    const int mb0 = tt * 128 + 32 * sq + 4 * g;
    f32x4 bias0 = *(const f32x4*)&mbias[mb0];
    f32x4 bias1 = *(const f32x4*)&mbias[mb0 + 16];
    float sv0[4], sv1[4];
#pragma unroll
    for (int rr = 0; rr < 4; ++rr) {
      sv0[rr] = a0[rr] + bias0[rr];
      sv1[rr] = a1[rr] + bias1[rr];
    }
    float tm = fmaxf(fmaxf(fmaxf(sv0[0], sv0[1]), fmaxf(sv0[2], sv0[3])),
                     fmaxf(fmaxf(sv1[0], sv1[1]), fmaxf(sv1[2], sv1[3])));
    tm = fmaxf(tm, __shfl_xor(tm, 16));
    tm = fmaxf(tm, __shfl_xor(tm, 32));
    const bool need = !__all(tm <= mr + 11.541560f);   // 8 * log2(e)
    if (need) {
      float mn = fmaxf(mr, tm);
      float esc = E2(mr - mn);
      lr *= esc; mr = mn;
      float fr[4];
#pragma unroll
      for (int rr = 0; rr < 4; ++rr) fr[rr] = __shfl(esc, 4 * g + rr);
#pragma unroll
      for (int n = 0; n < 5; ++n) {
#pragma unroll
        for (int rr = 0; rr < 4; ++rr) ctx[n][rr] *= fr[rr];
      }
    }
    float p0[4], p1[4];
#pragma unroll
    for (int rr = 0; rr < 4; ++rr) {
      p0[rr] = E2(sv0[rr] - mr);
      p1[rr] = E2(sv1[rr] - mr);
    }
    lr += ((p0[0] + p0[1]) + (p0[2] + p0[3])) + ((p1[0] + p1[1]) + (p1[2] + p1[3]));

    // ---- PV: full-K=32 MFMA (R14 two-cluster ordering). A slots j=0..3 <-
    //      blk0 rows 4g+j, j=4..7 <- blk1. B: tr-read(blk,n) -> slots 4blk+j. ----
    union { unsigned uu[4]; f16x8 v; } PA;
    PA.uu[0] = pkh(p0[0], p0[1]); PA.uu[1] = pkh(p0[2], p0[3]);
    PA.uu[2] = pkh(p1[0], p1[1]); PA.uu[3] = pkh(p1[2], p1[3]);
    const unsigned tra = trBase + (unsigned)(cur * 25344);
    {
      u16x4 ta0, tb0, ta1, tb1, ta2, tb2;
      asm volatile("ds_read_b64_tr_b16 %0, %1"             : "=v"(ta0) : "v"(tra));
      asm volatile("ds_read_b64_tr_b16 %0, %1 offset:3168" : "=v"(tb0) : "v"(tra));
      asm volatile("ds_read_b64_tr_b16 %0, %1 offset:528"  : "=v"(ta1) : "v"(tra));
      asm volatile("ds_read_b64_tr_b16 %0, %1 offset:3696" : "=v"(tb1) : "v"(tra));
      asm volatile("ds_read_b64_tr_b16 %0, %1 offset:1056" : "=v"(ta2) : "v"(tra));
      asm volatile("ds_read_b64_tr_b16 %0, %1 offset:4224" : "=v"(tb2) : "v"(tra));
      asm volatile("s_waitcnt lgkmcnt(0)" ::: "memory");
      __builtin_amdgcn_sched_barrier(0);
      union { u16 s[8]; f16x8 v; } B0, B1, B2;
#pragma unroll
      for (int j = 0; j < 4; ++j) {
        B0.s[j] = ta0[j]; B0.s[4 + j] = tb0[j];
        B1.s[j] = ta1[j]; B1.s[4 + j] = tb1[j];
        B2.s[j] = ta2[j]; B2.s[4 + j] = tb2[j];
      }
      ctx[0] = mfma16f(PA.v, B0.v, ctx[0]);
      ctx[1] = mfma16f(PA.v, B1.v, ctx[1]);
      ctx[2] = mfma16f(PA.v, B2.v, ctx[2]);
    }
    {
      u16x4 ta3, tb3, ta4, tb4;
      asm volatile("ds_read_b64_tr_b16 %0, %1 offset:1584" : "=v"(ta3) : "v"(tra));
      asm volatile("ds_read_b64_tr_b16 %0, %1 offset:4752" : "=v"(tb3) : "v"(tra));
      asm volatile("ds_read_b64_tr_b16 %0, %1 offset:2112" : "=v"(ta4) : "v"(tra));
      asm volatile("ds_read_b64_tr_b16 %0, %1 offset:5280" : "=v"(tb4) : "v"(tra));
      asm volatile("s_waitcnt lgkmcnt(0)" ::: "memory");
      __builtin_amdgcn_sched_barrier(0);
      union { u16 s[8]; f16x8 v; } B3, B4;
#pragma unroll
      for (int j = 0; j < 4; ++j) {
        B3.s[j] = ta3[j]; B3.s[4 + j] = tb3[j];
        B4.s[j] = ta4[j]; B4.s[4 + j] = tb4[j];
      }
      ctx[3] = mfma16f(PA.v, B3.v, ctx[3]);
      ctx[4] = mfma16f(PA.v, B4.v, ctx[4]);
    }

    if (hn) { STAGE_WRITE(nxt); }
    __syncthreads();
  }

  // ---------- epilogue: reduce lr, merge 4 s-slices, normalize, write ----------
  lr += __shfl_xor(lr, 16);
  lr += __shfl_xor(lr, 32);
  if (g == 0) {
    mst[sq * 32 + 16 * pp + l15] = mr;
    lst[sq * 32 + 16 * pp + l15] = lr;
  }
  __syncthreads();
  float F;
  {
    const int pi = 16 * pp + l15;
    float M = fmaxf(fmaxf(mst[pi], mst[32 + pi]), fmaxf(mst[64 + pi], mst[96 + pi]));
    F = E2(mr - M);
  }
  float gg[4];
#pragma unroll
  for (int rr = 0; rr < 4; ++rr) gg[rr] = __shfl(F, 4 * g + rr);
  float* cacc = (float*)smem;  // [32][84]
  for (int qq = 0; qq < 4; ++qq) {
    if (sq == qq) {
#pragma unroll
      for (int n = 0; n < 5; ++n) {
#pragma unroll
        for (int rr = 0; rr < 4; ++rr) {
          const int row = 16 * pp + 4 * g + rr;
          const int col = 16 * n + l15;
          float v = ctx[n][rr] * gg[rr];
          if (qq == 0) cacc[row * 84 + col] = v;
          else         cacc[row * 84 + col] += v;
        }
      }
    }
    __syncthreads();
  }
  {
    const int op = tid >> 4, oc = tid & 15;
    float Mv = fmaxf(fmaxf(mst[op], mst[32 + op]), fmaxf(mst[64 + op], mst[96 + op]));
    float Lv = lst[op] * E2(mst[op] - Mv) + lst[32 + op] * E2(mst[32 + op] - Mv)
             + lst[64 + op] * E2(mst[64 + op] - Mv) + lst[96 + op] * E2(mst[96 + op] - Mv);
    float inv = 1.0f / Lv;
    float* orow = out + ((size_t)bb * NP + 32 * phB + op) * ND + oc * 5;
    const float* crow = cacc + op * 84 + oc * 5;
#pragma unroll
    for (int i = 0; i < 5; ++i) orow[i] = crow[i] * inv;
  }
}

extern "C" void kernel_launch(void* const* d_in, const int* in_sizes, int n_in,
                              void* d_out, int out_size, void* d_ws, size_t ws_size,
                              hipStream_t stream) {
  (void)in_sizes; (void)n_in; (void)out_size; (void)d_ws; (void)ws_size;
  const float* enc  = (const float*)d_in[0];
  const float* dec  = (const float*)d_in[1];
  const int*   mask = (const int*)d_in[2];
  const float* W    = (const float*)d_in[3];
  float* out = (float*)d_out;
  DecoderAttention_62989990363717_kernel<<<dim3(512), dim3(NTHREADS), 0, stream>>>(
      enc, dec, mask, W, out);
}

// Round 17
// 48.199 us; speedup vs baseline: 1.3403x; 1.3403x over previous
//
#include <hip/hip_runtime.h>

#define NS 2048
#define NP 64
#define ND 80
#define LOG2E 1.4426950408889634f

typedef __attribute__((ext_vector_type(4))) float f32x4;
typedef __attribute__((ext_vector_type(2))) __fp16 fp16x2;
typedef __attribute__((ext_vector_type(8))) _Float16 f16x8;
typedef __attribute__((ext_vector_type(4))) unsigned short u16x4;
typedef unsigned short u16;

__device__ __forceinline__ float E2(float x) { return __builtin_amdgcn_exp2f(x); }
__device__ __forceinline__ unsigned pkh(float lo, float hi) {
  union { fp16x2 h; unsigned u; } cv;
  cv.h = __builtin_amdgcn_cvt_pkrtz(lo, hi);
  return cv.u;
}
__device__ __forceinline__ float f16f(u16 v) {
  union { u16 u; _Float16 h; } c; c.u = v; return (float)c.h;
}
// 16x16 K=32 f16 MFMA. C/D: col=lane&15, row=4*(lane>>4)+r.
// A/B share the (lane-group g, slot j) -> k=8g+j map (verified R2-R15).
__device__ __forceinline__ f32x4 mfma16f(f16x8 a, f16x8 b, f32x4 c) {
  return __builtin_amdgcn_mfma_f32_16x16x32_f16(a, b, c, 0, 0, 0);
}

// ====================== SPLIT kernel: 2 blocks per batch (s-halves) =========
// Per-wave code = R15 restricted to 64-row tiles (sq in {0,1}); all verified
// layout constants scaled: per-buf 6336 u16, quarter stride 1584 u16.
// LDS (bytes): ehP u16[2][6336] @0 (25344); mbias f32[1024] @25600;
//   mst f32[2][64] @29696; lst @30208; modep @30720; Wl f32[80][84] @30736
//   (ends 57616); overlays: dl f32[64][84]@0, qtmp f32[64][100]@0 (ends 25600),
//   cacc f32[64][84]@0.  57616 B/block -> exactly 2 blocks/CU (115 KB < 160 KB).
#define SP_SMEM 57616

__global__ __launch_bounds__(512, 4)
void da_split(const float* __restrict__ enc, const float* __restrict__ dec,
              const int* __restrict__ maskp, const float* __restrict__ W,
              u16* __restrict__ wsO, float* __restrict__ wsM,
              float* __restrict__ wsL)
{
  __shared__ __align__(16) char smem[SP_SMEM];
  u16* ehP    = (u16*)smem;               // [2][6336]
  float* mbias = (float*)(smem + 25600);  // [1024]
  float* mst  = (float*)(smem + 29696);   // [2][64]
  float* lst  = (float*)(smem + 30208);   // [2][64]
  int* modep  = (int*)(smem + 30720);

  const int tid  = (int)threadIdx.x;
  const int lane = tid & 63;
  const int wv   = tid >> 6;    // 0..7
  const int pp   = wv & 3;      // p-block: [16*pp, 16*pp+16)
  const int sq   = wv >> 2;     // 0..1: 32-row s-slice (quarters {2sq,2sq+1})
  const int l15  = lane & 15;
  const int g    = lane >> 4;
  const int bid  = (int)blockIdx.x;
  const int bb   = bid >> 1;    // batch
  const int sh   = bid & 1;     // s-half: rows [1024*sh, 1024*sh+1024)

  const float* encB = enc + ((size_t)bb * NS + 1024 * sh) * ND;
  const float* decB = dec + (size_t)bb * NP * ND;

  // ---------- prologue ----------
  {
    float* Wl = (float*)(smem + 30736);  // [80][84]
    float* dl = (float*)smem;            // [64][84]
    for (int i = tid; i < 80 * 80; i += 512) Wl[(i / 80) * 84 + (i % 80)] = W[i];
    for (int i = tid; i < 64 * 80; i += 512)
      dl[(i / 80) * 84 + (i % 80)] = decB[i] * LOG2E;
    if (tid == 0) {
      const unsigned* mw = (const unsigned*)maskp;
      int ok = 1;
      for (int i = 0; i < 16; ++i) ok &= (mw[i] <= 1u);
      *modep = ok;
    }
    __syncthreads();
    const int m32 = *modep;
    if (m32) {
      int v0 = maskp[(size_t)bb * NS + 1024 * sh + tid];
      int v1 = maskp[(size_t)bb * NS + 1024 * sh + tid + 512];
      mbias[tid]       = v0 ? -3.0e38f : 0.0f;
      mbias[tid + 512] = v1 ? -3.0e38f : 0.0f;
    } else if (tid < 256) {
      unsigned w = ((const unsigned*)maskp)[(size_t)bb * (NS / 4) + 256 * sh + tid];
      f32x4 bv;
      bv[0] = (w & 255u)         ? -3.0e38f : 0.0f;
      bv[1] = ((w >> 8) & 255u)  ? -3.0e38f : 0.0f;
      bv[2] = ((w >> 16) & 255u) ? -3.0e38f : 0.0f;
      bv[3] = (w >> 24)          ? -3.0e38f : 0.0f;
      *(f32x4*)&mbias[4 * tid] = bv;
    }
    // Q = dec @ W^T fp32: p = tid&63, e-range = 10*(tid>>6)
    float qa[10];
    const int qp = tid & 63, qw = tid >> 6;
#pragma unroll
    for (int j = 0; j < 10; ++j) qa[j] = 0.f;
    for (int kg = 0; kg < 20; ++kg) {
      f32x4 dv = *(const f32x4*)&dl[qp * 84 + kg * 4];
#pragma unroll
      for (int j = 0; j < 10; ++j) {
        f32x4 wv4 = *(const f32x4*)&Wl[(qw * 10 + j) * 84 + kg * 4];
        qa[j] = fmaf(dv.x, wv4.x, qa[j]);
        qa[j] = fmaf(dv.y, wv4.y, qa[j]);
        qa[j] = fmaf(dv.z, wv4.z, qa[j]);
        qa[j] = fmaf(dv.w, wv4.w, qa[j]);
      }
    }
    __syncthreads();
    float* qtmp = (float*)smem;  // [64][100]
#pragma unroll
    for (int j = 0; j < 10; ++j) qtmp[qp * 100 + qw * 10 + j] = qa[j];
    if (qw == 7) {
#pragma unroll
      for (int z = 0; z < 16; ++z) qtmp[qp * 100 + 80 + z] = 0.f;
    }
    __syncthreads();
  }

  // ---------- Q fragments ----------
  f16x8 qb[3];
  {
    const float* qtmp = (const float*)smem;
    const int prow = 16 * pp + l15;
#pragma unroll
    for (int kk = 0; kk < 3; ++kk) {
      const int d0 = kk * 32 + g * 8;
      f32x4 f0 = *(const f32x4*)&qtmp[prow * 100 + d0];
      f32x4 f1 = *(const f32x4*)&qtmp[prow * 100 + d0 + 4];
      union { _Float16 h[8]; f16x8 v; } H;
      H.h[0] = (_Float16)f0.x; H.h[1] = (_Float16)f0.y;
      H.h[2] = (_Float16)f0.z; H.h[3] = (_Float16)f0.w;
      H.h[4] = (_Float16)f1.x; H.h[5] = (_Float16)f1.y;
      H.h[6] = (_Float16)f1.z; H.h[7] = (_Float16)f1.w;
      qb[kk] = H.v;
    }
  }
  __syncthreads();

  // ---------- zero K-pad (n=5) once: 2 bufs x 4 quarters ----------
  if (tid < 128) {
    const int buf = tid >> 6, q = (tid >> 4) & 3, row = tid & 15;
    u16* p = ehP + buf * 6336 + (q * 6 + 5) * 264 + row * 16;
    *(uint4*)p = make_uint4(0u, 0u, 0u, 0u);
    *(uint4*)(p + 8) = make_uint4(0u, 0u, 0u, 0u);
  }

  // loaders: tid<320 (row = tid/5 in 0..63, c = tid%5)
  const bool ldr = (tid < 320);
  const int srow = tid / 5;
  const int c    = tid - srow * 5;
  u16* ePW = ehP + ((srow >> 4) * 6 + c) * 264 + (srow & 15) * 16;
  const float* gsrc = encB + srow * ND + 16 * c;

#define SP_STAGE(bi)                                                             \
  do {                                                                           \
    if (ldr) {                                                                   \
      unsigned hh[8];                                                            \
      hh[0] = pkh(r0.x, r0.y); hh[1] = pkh(r0.z, r0.w);                          \
      hh[2] = pkh(r1.x, r1.y); hh[3] = pkh(r1.z, r1.w);                          \
      hh[4] = pkh(r2.x, r2.y); hh[5] = pkh(r2.z, r2.w);                          \
      hh[6] = pkh(r3.x, r3.y); hh[7] = pkh(r3.z, r3.w);                          \
      u16* a_ = ePW + (bi) * 6336;                                               \
      *(uint4*)a_       = make_uint4(hh[0], hh[1], hh[2], hh[3]);                \
      *(uint4*)(a_ + 8) = make_uint4(hh[4], hh[5], hh[6], hh[7]);                \
    }                                                                            \
  } while (0)

  // stage tile 0
  {
    f32x4 r0, r1, r2, r3;
    if (ldr) {
      r0 = *(const f32x4*)gsrc;       r1 = *(const f32x4*)(gsrc + 4);
      r2 = *(const f32x4*)(gsrc + 8); r3 = *(const f32x4*)(gsrc + 12);
    }
    SP_STAGE(0);
    __syncthreads();
  }

  // ---------- main loop: 16 tiles of 64 rows ----------
  f32x4 ctx[5];
#pragma unroll
  for (int n = 0; n < 5; ++n) ctx[n] = (f32x4){0.f, 0.f, 0.f, 0.f};
  float mr = -1.0e30f, lr = 0.f;

  const int qkOff = (2 * sq) * 1584 + (g >> 1) * 264 + 16 * l15 + 8 * (g & 1);
  const unsigned trBase = (unsigned)(uintptr_t)ehP + (unsigned)(sq * 6336 + 8 * lane);

  for (int tt = 0; tt < 16; ++tt) {
    const int cur = tt & 1, nxt = cur ^ 1;
    const bool hn = (tt + 1 < 16);
    f32x4 r0, r1, r2, r3;
    if (hn && ldr) {
      const float* src = gsrc + (size_t)(tt + 1) * 64 * ND;
      r0 = *(const f32x4*)src;       r1 = *(const f32x4*)(src + 4);
      r2 = *(const f32x4*)(src + 8); r3 = *(const f32x4*)(src + 12);
    }

    // QK^T (swapped): two 16-row blocks, single-f16 Q
    f32x4 a0 = (f32x4){0.f, 0.f, 0.f, 0.f}, a1 = (f32x4){0.f, 0.f, 0.f, 0.f};
    {
      const u16* baseH0 = ehP + cur * 6336 + qkOff;
      const u16* baseH1 = baseH0 + 1584;
      f16x8 e0[3], e1[3];
#pragma unroll
      for (int kk = 0; kk < 3; ++kk) {
        e0[kk] = *(const f16x8*)(const void*)(baseH0 + kk * 528);
        e1[kk] = *(const f16x8*)(const void*)(baseH1 + kk * 528);
      }
#pragma unroll
      for (int kk = 0; kk < 3; ++kk) {
        a0 = mfma16f(e0[kk], qb[kk], a0);
        a1 = mfma16f(e1[kk], qb[kk], a1);
      }
    }

    const int mb0 = tt * 64 + 32 * sq + 4 * g;
    f32x4 bias0 = *(const f32x4*)&mbias[mb0];
    f32x4 bias1 = *(const f32x4*)&mbias[mb0 + 16];

    // issue all 10 PV tr-reads; latency hides under softmax
    const unsigned tra = trBase + (unsigned)(cur * 12672);
    u16x4 ta0, tb0, ta1, tb1, ta2, tb2, ta3, tb3, ta4, tb4;
    asm volatile("ds_read_b64_tr_b16 %0, %1"             : "=v"(ta0) : "v"(tra));
    asm volatile("ds_read_b64_tr_b16 %0, %1 offset:3168" : "=v"(tb0) : "v"(tra));
    asm volatile("ds_read_b64_tr_b16 %0, %1 offset:528"  : "=v"(ta1) : "v"(tra));
    asm volatile("ds_read_b64_tr_b16 %0, %1 offset:3696" : "=v"(tb1) : "v"(tra));
    asm volatile("ds_read_b64_tr_b16 %0, %1 offset:1056" : "=v"(ta2) : "v"(tra));
    asm volatile("ds_read_b64_tr_b16 %0, %1 offset:4224" : "=v"(tb2) : "v"(tra));
    asm volatile("ds_read_b64_tr_b16 %0, %1 offset:1584" : "=v"(ta3) : "v"(tra));
    asm volatile("ds_read_b64_tr_b16 %0, %1 offset:4752" : "=v"(tb3) : "v"(tra));
    asm volatile("ds_read_b64_tr_b16 %0, %1 offset:2112" : "=v"(ta4) : "v"(tra));
    asm volatile("ds_read_b64_tr_b16 %0, %1 offset:5280" : "=v"(tb4) : "v"(tra));

    // masked online softmax (exp2 domain), defer-max
    float sv0[4], sv1[4];
#pragma unroll
    for (int rr = 0; rr < 4; ++rr) {
      sv0[rr] = a0[rr] + bias0[rr];
      sv1[rr] = a1[rr] + bias1[rr];
    }
    float tm = fmaxf(fmaxf(fmaxf(sv0[0], sv0[1]), fmaxf(sv0[2], sv0[3])),
                     fmaxf(fmaxf(sv1[0], sv1[1]), fmaxf(sv1[2], sv1[3])));
    tm = fmaxf(tm, __shfl_xor(tm, 16));
    tm = fmaxf(tm, __shfl_xor(tm, 32));
    const bool need = !__all(tm <= mr + 11.541560f);
    if (need) {
      float mn = fmaxf(mr, tm);
      float esc = E2(mr - mn);
      lr *= esc; mr = mn;
      float fr[4];
#pragma unroll
      for (int rr = 0; rr < 4; ++rr) fr[rr] = __shfl(esc, 4 * g + rr);
#pragma unroll
      for (int n = 0; n < 5; ++n) {
#pragma unroll
        for (int rr = 0; rr < 4; ++rr) ctx[n][rr] *= fr[rr];
      }
    }
    float p0[4], p1[4];
#pragma unroll
    for (int rr = 0; rr < 4; ++rr) {
      p0[rr] = E2(sv0[rr] - mr);
      p1[rr] = E2(sv1[rr] - mr);
    }
    lr += ((p0[0] + p0[1]) + (p0[2] + p0[3])) + ((p1[0] + p1[1]) + (p1[2] + p1[3]));

    // PV full-K=32
    union { unsigned uu[4]; f16x8 v; } PA;
    PA.uu[0] = pkh(p0[0], p0[1]); PA.uu[1] = pkh(p0[2], p0[3]);
    PA.uu[2] = pkh(p1[0], p1[1]); PA.uu[3] = pkh(p1[2], p1[3]);
    asm volatile("s_waitcnt lgkmcnt(0)" ::: "memory");
    __builtin_amdgcn_sched_barrier(0);
    {
      union { u16 s[8]; f16x8 v; } B0, B1, B2, B3, B4;
#pragma unroll
      for (int j = 0; j < 4; ++j) {
        B0.s[j] = ta0[j]; B0.s[4 + j] = tb0[j];
        B1.s[j] = ta1[j]; B1.s[4 + j] = tb1[j];
        B2.s[j] = ta2[j]; B2.s[4 + j] = tb2[j];
        B3.s[j] = ta3[j]; B3.s[4 + j] = tb3[j];
        B4.s[j] = ta4[j]; B4.s[4 + j] = tb4[j];
      }
      ctx[0] = mfma16f(PA.v, B0.v, ctx[0]);
      ctx[1] = mfma16f(PA.v, B1.v, ctx[1]);
      ctx[2] = mfma16f(PA.v, B2.v, ctx[2]);
      ctx[3] = mfma16f(PA.v, B3.v, ctx[3]);
      ctx[4] = mfma16f(PA.v, B4.v, ctx[4]);
    }

    if (hn) { SP_STAGE(nxt); }
    __syncthreads();
  }

  // ---------- epilogue: merge 2 s-slices, self-normalize, write partial ----------
  lr += __shfl_xor(lr, 16);
  lr += __shfl_xor(lr, 32);
  if (g == 0) {
    mst[sq * 64 + 16 * pp + l15] = mr;
    lst[sq * 64 + 16 * pp + l15] = lr;
  }
  __syncthreads();
  float F;
  {
    const int pi = 16 * pp + l15;
    float M = fmaxf(mst[pi], mst[64 + pi]);
    F = E2(mr - M);
  }
  float gg[4];
#pragma unroll
  for (int rr = 0; rr < 4; ++rr) gg[rr] = __shfl(F, 4 * g + rr);
  float* cacc = (float*)smem;  // [64][84]
  for (int qq = 0; qq < 2; ++qq) {
    if (sq == qq) {
#pragma unroll
      for (int n = 0; n < 5; ++n) {
#pragma unroll
        for (int rr = 0; rr < 4; ++rr) {
          const int row = 16 * pp + 4 * g + rr;
          const int col = 16 * n + l15;
          float v = ctx[n][rr] * gg[rr];
          if (qq == 0) cacc[row * 84 + col] = v;
          else         cacc[row * 84 + col] += v;
        }
      }
    }
    __syncthreads();
  }
  if (tid < 64) {
    const int p = tid;
    float Mv = fmaxf(mst[p], mst[64 + p]);
    float Lv = lst[p] * E2(mst[p] - Mv) + lst[64 + p] * E2(mst[64 + p] - Mv);
    wsM[bid * 64 + p] = Mv;
    wsL[bid * 64 + p] = Lv;
  }
  {
    const int op = tid >> 3, oc = tid & 7;
    float Mv = fmaxf(mst[op], mst[64 + op]);
    float Lv = lst[op] * E2(mst[op] - Mv) + lst[64 + op] * E2(mst[64 + op] - Mv);
    float inv = (Lv > 0.f) ? 1.0f / Lv : 0.f;   // fully-masked half guard
    const float* crow = cacc + op * 84 + oc * 10;
    u16* dst = wsO + (size_t)bid * 5120 + op * 80 + oc * 10;
#pragma unroll
    for (int k = 0; k < 10; k += 2)
      *(unsigned*)&dst[k] = pkh(crow[k] * inv, crow[k + 1] * inv);
  }
}

// ====================== MERGE kernel ======================
__global__ __launch_bounds__(512)
void da_merge(const u16* __restrict__ wsO, const float* __restrict__ wsM,
              const float* __restrict__ wsL, float* __restrict__ out)
{
  const int bb  = (int)blockIdx.x;
  const int tid = (int)threadIdx.x;
  const int p   = tid >> 3, i = tid & 7;
  float mA = wsM[bb * 128 + p],      mB = wsM[bb * 128 + 64 + p];
  float lA = wsL[bb * 128 + p],      lB = wsL[bb * 128 + 64 + p];
  float M  = fmaxf(mA, mB);
  float wA = lA * E2(mA - M), wB = lB * E2(mB - M);
  float inv = 1.0f / (wA + wB);   // half A always has s=0 unmasked -> wA>0
  const u16* a  = wsO + (size_t)(bb * 2) * 5120 + p * 80 + i * 10;
  const u16* b2 = a + 5120;
  float* o = out + (size_t)bb * 5120 + p * 80 + i * 10;
#pragma unroll
  for (int k = 0; k < 10; k += 2) {
    float2 v;
    v.x = (f16f(a[k])     * wA + f16f(b2[k])     * wB) * inv;
    v.y = (f16f(a[k + 1]) * wA + f16f(b2[k + 1]) * wB) * inv;
    *(float2*)&o[k] = v;
  }
}

// ====================== MONO fallback (R15, verified 39.9us) ======================
#define MO_SMEM 60944
__global__ __launch_bounds__(1024, 4)
void da_mono(const float* __restrict__ enc, const float* __restrict__ dec,
             const int* __restrict__ maskp, const float* __restrict__ W,
             float* __restrict__ out)
{
  __shared__ __align__(16) char smem[MO_SMEM];
  u16* ehP    = (u16*)smem;               // [2][12672]
  float* mbias = (float*)(smem + 50688);
  float* mst  = (float*)(smem + 58880);
  float* lst  = (float*)(smem + 59904);
  int* modep  = (int*)(smem + 60928);

  const int tid  = (int)threadIdx.x;
  const int lane = tid & 63;
  const int wv   = tid >> 6;
  const int pp   = wv & 3;
  const int sq   = wv >> 2;
  const int l15  = lane & 15;
  const int g    = lane >> 4;
  const int b    = (int)blockIdx.x;

  const float* encB = enc + (size_t)b * NS * ND;
  const float* decB = dec + (size_t)b * NP * ND;

  {
    float* Wl = (float*)smem;
    float* dl = (float*)(smem + 26880);
    for (int i = tid; i < 80 * 80; i += 1024) Wl[(i / 80) * 84 + (i % 80)] = W[i];
    for (int i = tid; i < 64 * 80; i += 1024)
      dl[(i / 80) * 84 + (i % 80)] = decB[i] * LOG2E;
    if (tid == 0) {
      const unsigned* mw = (const unsigned*)maskp;
      int ok = 1;
      for (int i = 0; i < 16; ++i) ok &= (mw[i] <= 1u);
      *modep = ok;
    }
    __syncthreads();
    const int m32 = *modep;
    if (m32) {
      int v0 = maskp[(size_t)b * NS + tid];
      int v1 = maskp[(size_t)b * NS + tid + 1024];
      mbias[tid]        = v0 ? -3.0e38f : 0.0f;
      mbias[tid + 1024] = v1 ? -3.0e38f : 0.0f;
    } else if (tid < 512) {
      unsigned w = ((const unsigned*)maskp)[(size_t)b * (NS / 4) + tid];
      f32x4 bb;
      bb[0] = (w & 255u)         ? -3.0e38f : 0.0f;
      bb[1] = ((w >> 8) & 255u)  ? -3.0e38f : 0.0f;
      bb[2] = ((w >> 16) & 255u) ? -3.0e38f : 0.0f;
      bb[3] = (w >> 24)          ? -3.0e38f : 0.0f;
      *(f32x4*)&mbias[4 * tid] = bb;
    }
    float qa[5];
    const int qp = tid & 63, qw = tid >> 6;
#pragma unroll
    for (int j = 0; j < 5; ++j) qa[j] = 0.f;
    for (int kg = 0; kg < 20; ++kg) {
      f32x4 dv = *(const f32x4*)&dl[qp * 84 + kg * 4];
#pragma unroll
      for (int j = 0; j < 5; ++j) {
        f32x4 wv4 = *(const f32x4*)&Wl[(qw * 5 + j) * 84 + kg * 4];
        qa[j] = fmaf(dv.x, wv4.x, qa[j]);
        qa[j] = fmaf(dv.y, wv4.y, qa[j]);
        qa[j] = fmaf(dv.z, wv4.z, qa[j]);
        qa[j] = fmaf(dv.w, wv4.w, qa[j]);
      }
    }
    __syncthreads();
    float* qtmp = (float*)smem;
#pragma unroll
    for (int j = 0; j < 5; ++j) qtmp[qp * 100 + qw * 5 + j] = qa[j];
    if (qw == 15) {
#pragma unroll
      for (int z = 0; z < 16; ++z) qtmp[qp * 100 + 80 + z] = 0.f;
    }
    __syncthreads();
  }

  f16x8 qb[3];
  {
    const float* qtmp = (const float*)smem;
    const int prow = 16 * pp + l15;
#pragma unroll
    for (int kk = 0; kk < 3; ++kk) {
      const int d0 = kk * 32 + g * 8;
      f32x4 f0 = *(const f32x4*)&qtmp[prow * 100 + d0];
      f32x4 f1 = *(const f32x4*)&qtmp[prow * 100 + d0 + 4];
      union { _Float16 h[8]; f16x8 v; } H;
      H.h[0] = (_Float16)f0.x; H.h[1] = (_Float16)f0.y;
      H.h[2] = (_Float16)f0.z; H.h[3] = (_Float16)f0.w;
      H.h[4] = (_Float16)f1.x; H.h[5] = (_Float16)f1.y;
      H.h[6] = (_Float16)f1.z; H.h[7] = (_Float16)f1.w;
      qb[kk] = H.v;
    }
  }
  __syncthreads();

  if (tid < 256) {
    const int buf = tid >> 7, q = (tid >> 4) & 7, row = tid & 15;
    u16* p = ehP + buf * 12672 + (q * 6 + 5) * 264 + row * 16;
    *(uint4*)p = make_uint4(0u, 0u, 0u, 0u);
    *(uint4*)(p + 8) = make_uint4(0u, 0u, 0u, 0u);
  }

  const bool ldr = (tid < 640);
  const int srow = tid / 5;
  const int c    = tid - srow * 5;
  u16* ePW = ehP + ((srow >> 4) * 6 + c) * 264 + (srow & 15) * 16;
  const float* gsrc = encB + srow * ND + 16 * c;

#define MO_STAGE(bi)                                                             \
  do {                                                                           \
    if (ldr) {                                                                   \
      unsigned hh[8];                                                            \
      hh[0] = pkh(r0.x, r0.y); hh[1] = pkh(r0.z, r0.w);                          \
      hh[2] = pkh(r1.x, r1.y); hh[3] = pkh(r1.z, r1.w);                          \
      hh[4] = pkh(r2.x, r2.y); hh[5] = pkh(r2.z, r2.w);                          \
      hh[6] = pkh(r3.x, r3.y); hh[7] = pkh(r3.z, r3.w);                          \
      u16* a_ = ePW + (bi) * 12672;                                              \
      *(uint4*)a_       = make_uint4(hh[0], hh[1], hh[2], hh[3]);                \
      *(uint4*)(a_ + 8) = make_uint4(hh[4], hh[5], hh[6], hh[7]);                \
    }                                                                            \
  } while (0)

  {
    f32x4 r0, r1, r2, r3;
    if (ldr) {
      r0 = *(const f32x4*)gsrc;       r1 = *(const f32x4*)(gsrc + 4);
      r2 = *(const f32x4*)(gsrc + 8); r3 = *(const f32x4*)(gsrc + 12);
    }
    MO_STAGE(0);
    __syncthreads();
  }

  f32x4 ctx[5];
#pragma unroll
  for (int n = 0; n < 5; ++n) ctx[n] = (f32x4){0.f, 0.f, 0.f, 0.f};
  float mr = -1.0e30f, lr = 0.f;

  const int qkOff = (2 * sq) * 1584 + (g >> 1) * 264 + 16 * l15 + 8 * (g & 1);
  const unsigned trBase = (unsigned)(uintptr_t)ehP + (unsigned)(sq * 6336 + 8 * lane);

  for (int tt = 0; tt < 16; ++tt) {
    const int cur = tt & 1, nxt = cur ^ 1;
    const bool hn = (tt + 1 < 16);
    f32x4 r0, r1, r2, r3;
    if (hn && ldr) {
      const float* src = gsrc + (size_t)(tt + 1) * 128 * ND;
      r0 = *(const f32x4*)src;       r1 = *(const f32x4*)(src + 4);
      r2 = *(const f32x4*)(src + 8); r3 = *(const f32x4*)(src + 12);
    }

    f32x4 a0 = (f32x4){0.f, 0.f, 0.f, 0.f}, a1 = (f32x4){0.f, 0.f, 0.f, 0.f};
    {
      const u16* baseH0 = ehP + cur * 12672 + qkOff;
      const u16* baseH1 = baseH0 + 1584;
      f16x8 e0[3], e1[3];
#pragma unroll
      for (int kk = 0; kk < 3; ++kk) {
        e0[kk] = *(const f16x8*)(const void*)(baseH0 + kk * 528);
        e1[kk] = *(const f16x8*)(const void*)(baseH1 + kk * 528);
      }
#pragma unroll
      for (int kk = 0; kk < 3; ++kk) {
        a0 = mfma16f(e0[kk], qb[kk], a0);
        a1 = mfma16f(e1[kk], qb[kk], a1);
      }
    }

    const int mb0 = tt * 128 + 32 * sq + 4 * g;
    f32x4 bias0 = *(const f32x4*)&mbias[mb0];
    f32x4 bias1 = *(const f32x4*)&mbias[mb0 + 16];

    const unsigned tra = trBase + (unsigned)(cur * 25344);
    u16x4 ta0, tb0, ta1, tb1, ta2, tb2, ta3, tb3, ta4, tb4;
    asm volatile("ds_read_b64_tr_b16 %0, %1"             : "=v"(ta0) : "v"(tra));
    asm volatile("ds_read_b64_tr_b16 %0, %1 offset:3168" : "=v"(tb0) : "v"(tra));
    asm volatile("ds_read_b64_tr_b16 %0, %1 offset:528"  : "=v"(ta1) : "v"(tra));
    asm volatile("ds_read_b64_tr_b16 %0, %1 offset:3696" : "=v"(tb1) : "v"(tra));
    asm volatile("ds_read_b64_tr_b16 %0, %1 offset:1056" : "=v"(ta2) : "v"(tra));
    asm volatile("ds_read_b64_tr_b16 %0, %1 offset:4224" : "=v"(tb2) : "v"(tra));
    asm volatile("ds_read_b64_tr_b16 %0, %1 offset:1584" : "=v"(ta3) : "v"(tra));
    asm volatile("ds_read_b64_tr_b16 %0, %1 offset:4752" : "=v"(tb3) : "v"(tra));
    asm volatile("ds_read_b64_tr_b16 %0, %1 offset:2112" : "=v"(ta4) : "v"(tra));
    asm volatile("ds_read_b64_tr_b16 %0, %1 offset:5280" : "=v"(tb4) : "v"(tra));

    float sv0[4], sv1[4];
#pragma unroll
    for (int rr = 0; rr < 4; ++rr) {
      sv0[rr] = a0[rr] + bias0[rr];
      sv1[rr] = a1[rr] + bias1[rr];
    }
    float tm = fmaxf(fmaxf(fmaxf(sv0[0], sv0[1]), fmaxf(sv0[2], sv0[3])),
                     fmaxf(fmaxf(sv1[0], sv1[1]), fmaxf(sv1[2], sv1[3])));
    tm = fmaxf(tm, __shfl_xor(tm, 16));
    tm = fmaxf(tm, __shfl_xor(tm, 32));
    const bool need = !__all(tm <= mr + 11.541560f);
    if (need) {
      float mn = fmaxf(mr, tm);
      float esc = E2(mr - mn);
      lr *= esc; mr = mn;
      float fr[4];
#pragma unroll
      for (int rr = 0; rr < 4; ++rr) fr[rr] = __shfl(esc, 4 * g + rr);
#pragma unroll
      for (int n = 0; n < 5; ++n) {
#pragma unroll
        for (int rr = 0; rr < 4; ++rr) ctx[n][rr] *= fr[rr];
      }
    }
    float p0[4], p1[4];
#pragma unroll
    for (int rr = 0; rr < 4; ++rr) {
      p0[rr] = E2(sv0[rr] - mr);
      p1[rr] = E2(sv1[rr] - mr);
    }
    lr += ((p0[0] + p0[1]) + (p0[2] + p0[3])) + ((p1[0] + p1[1]) + (p1[2] + p1[3]));

    union { unsigned uu[4]; f16x8 v; } PA;
    PA.uu[0] = pkh(p0[0], p0[1]); PA.uu[1] = pkh(p0[2], p0[3]);
    PA.uu[2] = pkh(p1[0], p1[1]); PA.uu[3] = pkh(p1[2], p1[3]);
    asm volatile("s_waitcnt lgkmcnt(0)" ::: "memory");
    __builtin_amdgcn_sched_barrier(0);
    {
      union { u16 s[8]; f16x8 v; } B0, B1, B2, B3, B4;
#pragma unroll
      for (int j = 0; j < 4; ++j) {
        B0.s[j] = ta0[j]; B0.s[4 + j] = tb0[j];
        B1.s[j] = ta1[j]; B1.s[4 + j] = tb1[j];
        B2.s[j] = ta2[j]; B2.s[4 + j] = tb2[j];
        B3.s[j] = ta3[j]; B3.s[4 + j] = tb3[j];
        B4.s[j] = ta4[j]; B4.s[4 + j] = tb4[j];
      }
      ctx[0] = mfma16f(PA.v, B0.v, ctx[0]);
      ctx[1] = mfma16f(PA.v, B1.v, ctx[1]);
      ctx[2] = mfma16f(PA.v, B2.v, ctx[2]);
      ctx[3] = mfma16f(PA.v, B3.v, ctx[3]);
      ctx[4] = mfma16f(PA.v, B4.v, ctx[4]);
    }

    if (hn) { MO_STAGE(nxt); }
    __syncthreads();
  }

  lr += __shfl_xor(lr, 16);
  lr += __shfl_xor(lr, 32);
  if (g == 0) {
    mst[sq * 64 + 16 * pp + l15] = mr;
    lst[sq * 64 + 16 * pp + l15] = lr;
  }
  __syncthreads();
  float F;
  {
    const int pi = 16 * pp + l15;
    float M = fmaxf(fmaxf(mst[pi], mst[64 + pi]), fmaxf(mst[128 + pi], mst[192 + pi]));
    F = E2(mr - M);
  }
  float gg[4];
#pragma unroll
  for (int rr = 0; rr < 4; ++rr) gg[rr] = __shfl(F, 4 * g + rr);
  float* cacc = (float*)smem;
  for (int qq = 0; qq < 4; ++qq) {
    if (sq == qq) {
#pragma unroll
      for (int n = 0; n < 5; ++n) {
#pragma unroll
        for (int rr = 0; rr < 4; ++rr) {
          const int row = 16 * pp + 4 * g + rr;
          const int col = 16 * n + l15;
          float v = ctx[n][rr] * gg[rr];
          if (qq == 0) cacc[row * 84 + col] = v;
          else         cacc[row * 84 + col] += v;
        }
      }
    }
    __syncthreads();
  }
  {
    const int op = tid >> 4, oc = tid & 15;
    float Mv = fmaxf(fmaxf(mst[op], mst[64 + op]), fmaxf(mst[128 + op], mst[192 + op]));
    float Lv = lst[op] * E2(mst[op] - Mv) + lst[64 + op] * E2(mst[64 + op] - Mv)
             + lst[128 + op] * E2(mst[128 + op] - Mv) + lst[192 + op] * E2(mst[192 + op] - Mv);
    float inv = 1.0f / Lv;
    float* orow = out + ((size_t)b * NP + op) * ND + oc * 5;
    const float* crow = cacc + op * 84 + oc * 5;
#pragma unroll
    for (int i = 0; i < 5; ++i) orow[i] = crow[i] * inv;
  }
}

extern "C" void kernel_launch(void* const* d_in, const int* in_sizes, int n_in,
                              void* d_out, int out_size, void* d_ws, size_t ws_size,
                              hipStream_t stream) {
  (void)in_sizes; (void)n_in; (void)out_size;
  const float* enc  = (const float*)d_in[0];
  const float* dec  = (const float*)d_in[1];
  const int*   mask = (const int*)d_in[2];
  const float* W    = (const float*)d_in[3];
  float* out = (float*)d_out;
  const size_t WS_NEEDED = (size_t)512 * 5120 * 2 + (size_t)2 * 512 * 64 * 4;
  if (ws_size >= WS_NEEDED) {
    u16* wsO   = (u16*)d_ws;
    float* wsM = (float*)((char*)d_ws + (size_t)512 * 5120 * 2);
    float* wsL = wsM + 512 * 64;
    da_split<<<dim3(512), dim3(512), 0, stream>>>(enc, dec, mask, W, wsO, wsM, wsL);
    da_merge<<<dim3(256), dim3(512), 0, stream>>>(wsO, wsM, wsL, out);
  } else {
    da_mono<<<dim3(256), dim3(1024), 0, stream>>>(enc, dec, mask, W, out);
  }
}

// Round 18
// 42.142 us; speedup vs baseline: 1.5329x; 1.1437x over previous
//
#include <hip/hip_runtime.h>

#define NS 2048
#define NP 64
#define ND 80
#define NTHREADS 1024
#define LOG2E 1.4426950408889634f
#define BUFU 12672          // u16 per enc buffer

typedef __attribute__((ext_vector_type(4))) float f32x4;
typedef __attribute__((ext_vector_type(2))) __fp16 fp16x2;
typedef __attribute__((ext_vector_type(8))) _Float16 f16x8;
typedef __attribute__((ext_vector_type(4))) unsigned short u16x4;
typedef unsigned short u16;

// ---------------- LDS layout (bytes) ----------------
// ehP  u16[4][12672] @ 0       (101376)  f16 enc, 16x16 [s][d] row-major regions;
//        region(q,n) = (q*6+n)*264 u16; q = s>>4; n=5 = K-pad (zeroed once).
//        QUAD buffered: pair kp computes tiles {2kp,2kp+1} from bufs {rb,rb+1}
//        (rb = (kp&1)*2) while staging tiles {2kp+2,2kp+3} into bufs {wb,wb+1}
//        (wb = 2-rb). ONE barrier per pair -> waves drift a tile apart.
// bitm u32[64]  @ 101376 (256)   mask bitmask, bit s = masked (built by ballot)
// mst  f32[4][64] @ 101632 ; lst @ 102656 ; modep @ 103680
// prologue overlay: W f32[80][84]@0 ; dec f32[64][84]@26880 ; qtmp f32[64][100]@0
// epilogue overlay: cacc f32[64][84]@0
#define SMEM_BYTES 103684

__device__ __forceinline__ float E2(float x) { return __builtin_amdgcn_exp2f(x); }
__device__ __forceinline__ unsigned pkh(float lo, float hi) {
  union { fp16x2 h; unsigned u; } cv;
  cv.h = __builtin_amdgcn_cvt_pkrtz(lo, hi);
  return cv.u;
}
// 16x16 K=32 f16 MFMA. C/D: col=lane&15, row=4*(lane>>4)+r (dtype-independent).
// A/B share the (lane-group g, slot j) -> k=8g+j map (verified R2-R15).
__device__ __forceinline__ f32x4 mfma16f(f16x8 a, f16x8 b, f32x4 c) {
  return __builtin_amdgcn_mfma_f32_16x16x32_f16(a, b, c, 0, 0, 0);
}

__global__ __launch_bounds__(NTHREADS, 4)
void DecoderAttention_62989990363717_kernel(const float* __restrict__ enc,
                                            const float* __restrict__ dec,
                                            const int* __restrict__ maskp,
                                            const float* __restrict__ W,
                                            float* __restrict__ out)
{
  __shared__ __align__(16) char smem[SMEM_BYTES];

  u16* ehP      = (u16*)smem;                  // [4][12672]
  unsigned* bitm = (unsigned*)(smem + 101376); // [64]
  float* mst    = (float*)(smem + 101632);     // [4][64]
  float* lst    = (float*)(smem + 102656);     // [4][64]
  int* modep    = (int*)(smem + 103680);

  const int tid  = (int)threadIdx.x;
  const int lane = tid & 63;
  const int wv   = tid >> 6;    // 0..15
  const int pp   = wv & 3;      // p-block: rows [16*pp, 16*pp+16)
  const int sq   = wv >> 2;     // 32-row s-slice within tile: quarters {2sq, 2sq+1}
  const int l15  = lane & 15;
  const int g    = lane >> 4;
  const int b    = (int)blockIdx.x;
  const float NEGINF = __uint_as_float(0xFF800000u);

  const float* encB = enc + (size_t)b * NS * ND;
  const float* decB = dec + (size_t)b * NP * ND;

  // ---------- prologue: W, dec(scaled) -> LDS; mask ballot; Q ----------
  {
    float* Wl = (float*)smem;            // [80][84]
    float* dl = (float*)(smem + 26880);  // [64][84]
    for (int i = tid; i < 80 * 80; i += NTHREADS) Wl[(i / 80) * 84 + (i % 80)] = W[i];
    for (int i = tid; i < 64 * 80; i += NTHREADS)
      dl[(i / 80) * 84 + (i % 80)] = decB[i] * LOG2E;   // exp2-domain scores
    if (tid == 0) {
      const unsigned* mw = (const unsigned*)maskp;
      int ok = 1;
      for (int i = 0; i < 16; ++i) ok &= (mw[i] <= 1u);
      *modep = ok;   // 1 => int32 mask, 0 => int8 mask
    }
    __syncthreads();
    // mask -> bitmask via wave ballot (wave wv covers s = 64*wv .. 64*wv+63)
    {
      const int m32 = *modep;
      int v0, v1;
      if (m32) {
        v0 = maskp[(size_t)b * NS + tid] != 0;
        v1 = maskp[(size_t)b * NS + tid + 1024] != 0;
      } else {
        const unsigned char* m8 = (const unsigned char*)maskp;
        v0 = m8[(size_t)b * NS + tid] != 0;
        v1 = m8[(size_t)b * NS + tid + 1024] != 0;
      }
      unsigned long long b0 = __ballot(v0);
      unsigned long long b1 = __ballot(v1);
      if (lane == 0) {
        *(unsigned long long*)&bitm[2 * wv]      = b0;
        *(unsigned long long*)&bitm[32 + 2 * wv] = b1;
      }
    }
    // Q = dec @ W^T in fp32 (all 1024 threads: p = tid&63, e-range = 5*qw)
    float qa[5];
    const int qp = tid & 63, qw = tid >> 6;   // qw 0..15
#pragma unroll
    for (int j = 0; j < 5; ++j) qa[j] = 0.f;
    for (int kg = 0; kg < 20; ++kg) {
      f32x4 dv = *(const f32x4*)&dl[qp * 84 + kg * 4];
#pragma unroll
      for (int j = 0; j < 5; ++j) {
        f32x4 wv4 = *(const f32x4*)&Wl[(qw * 5 + j) * 84 + kg * 4];
        qa[j] = fmaf(dv.x, wv4.x, qa[j]);
        qa[j] = fmaf(dv.y, wv4.y, qa[j]);
        qa[j] = fmaf(dv.z, wv4.z, qa[j]);
        qa[j] = fmaf(dv.w, wv4.w, qa[j]);
      }
    }
    __syncthreads();            // Wl/dl reads done
    float* qtmp = (float*)smem; // [64][100], zeros at d=80..95
#pragma unroll
    for (int j = 0; j < 5; ++j) qtmp[qp * 100 + qw * 5 + j] = qa[j];
    if (qw == 15) {
#pragma unroll
      for (int z = 0; z < 16; ++z) qtmp[qp * 100 + 80 + z] = 0.f;
    }
    __syncthreads();
  }

  // ---------- Q fragments (persistent, single f16 RNE) ----------
  f16x8 qb[3];
  {
    const float* qtmp = (const float*)smem;
    const int prow = 16 * pp + l15;
#pragma unroll
    for (int kk = 0; kk < 3; ++kk) {
      const int d0 = kk * 32 + g * 8;
      f32x4 f0 = *(const f32x4*)&qtmp[prow * 100 + d0];
      f32x4 f1 = *(const f32x4*)&qtmp[prow * 100 + d0 + 4];
      union { _Float16 h[8]; f16x8 v; } H;
      H.h[0] = (_Float16)f0.x; H.h[1] = (_Float16)f0.y;
      H.h[2] = (_Float16)f0.z; H.h[3] = (_Float16)f0.w;
      H.h[4] = (_Float16)f1.x; H.h[5] = (_Float16)f1.y;
      H.h[6] = (_Float16)f1.z; H.h[7] = (_Float16)f1.w;
      qb[kk] = H.v;
    }
  }
  __syncthreads();   // qtmp dead; staging may overwrite

  // ---------- zero K-pad regions (n=5) once: 4 buffers x 8 quarters ----------
  if (tid < 512) {
    const int buf = tid >> 7, q = (tid >> 4) & 7, row = tid & 15;
    u16* p = ehP + buf * BUFU + (q * 6 + 5) * 264 + row * 16;
    *(uint4*)p = make_uint4(0u, 0u, 0u, 0u);
    *(uint4*)(p + 8) = make_uint4(0u, 0u, 0u, 0u);
  }

  // loader roles: tid<640 stage enc (5 threads/row, 16 f32 each, all-b128 writes)
  const bool ldr = (tid < 640);
  const int srow = tid / 5;                 // 0..127
  const int c    = tid - srow * 5;          // 0..4 (d-block of 16)
  u16* ePW = ehP + ((srow >> 4) * 6 + c) * 264 + (srow & 15) * 16;
  const float* gsrc = encB + srow * ND + 16 * c;

#define LOAD_T(T)                                                                \
  do {                                                                           \
    const float* src = gsrc + (size_t)(T) * 128 * ND;                            \
    r0 = *(const f32x4*)src;       r1 = *(const f32x4*)(src + 4);                \
    r2 = *(const f32x4*)(src + 8); r3 = *(const f32x4*)(src + 12);               \
  } while (0)

#define STAGE_WRITE(bi)                                                          \
  do {                                                                           \
    unsigned hh[8];                                                              \
    hh[0] = pkh(r0.x, r0.y); hh[1] = pkh(r0.z, r0.w);                            \
    hh[2] = pkh(r1.x, r1.y); hh[3] = pkh(r1.z, r1.w);                            \
    hh[4] = pkh(r2.x, r2.y); hh[5] = pkh(r2.z, r2.w);                            \
    hh[6] = pkh(r3.x, r3.y); hh[7] = pkh(r3.z, r3.w);                            \
    u16* a_ = ePW + (bi) * BUFU;                                                 \
    *(uint4*)a_       = make_uint4(hh[0], hh[1], hh[2], hh[3]);                  \
    *(uint4*)(a_ + 8) = make_uint4(hh[4], hh[5], hh[6], hh[7]);                  \
  } while (0)

  // ---------- stage tiles 0 -> buf0, 1 -> buf1 ----------
  {
    f32x4 r0, r1, r2, r3;
    if (ldr) { LOAD_T(0); STAGE_WRITE(0); LOAD_T(1); STAGE_WRITE(1); }
    __syncthreads();
  }

  // ---------- main loop: 8 pairs of tiles, 1 barrier per pair ----------
  f32x4 ctx[5];
#pragma unroll
  for (int n = 0; n < 5; ++n) ctx[n] = (f32x4){0.f, 0.f, 0.f, 0.f};
  // mr init -1e30: masked rows (sv=-inf) underflow to 0 in all orders.
  float mr = -1.0e30f, lr = 0.f;

  // QK A-frag base (u16): region(2sq+blk, (g>>1)+2kk) + 16*l15 + 8*(g&1)
  const int qkOff = (2 * sq) * 1584 + (g >> 1) * 264 + 16 * l15 + 8 * (g & 1);
  // PV tr-read base (bytes): region(2sq, n) + 8*lane; blk1 = +3168B, n-step = 528B
  const unsigned trBase = (unsigned)(uintptr_t)ehP + (unsigned)(sq * 6336 + 8 * lane);
  const int msh0 = 4 * g, msh1 = 16 + 4 * g;

#define TILE_BODY(TT, BI)                                                        \
  {                                                                              \
    const int bO = (BI) * BUFU;                                                  \
    f32x4 a0 = (f32x4){0.f,0.f,0.f,0.f}, a1 = (f32x4){0.f,0.f,0.f,0.f};          \
    {                                                                            \
      const u16* baseH0 = ehP + bO + qkOff;                                      \
      const u16* baseH1 = baseH0 + 1584;                                         \
      f16x8 e00 = *(const f16x8*)(const void*)(baseH0);                          \
      f16x8 e01 = *(const f16x8*)(const void*)(baseH0 + 528);                    \
      f16x8 e02 = *(const f16x8*)(const void*)(baseH0 + 1056);                   \
      f16x8 e10 = *(const f16x8*)(const void*)(baseH1);                          \
      f16x8 e11 = *(const f16x8*)(const void*)(baseH1 + 528);                    \
      f16x8 e12 = *(const f16x8*)(const void*)(baseH1 + 1056);                   \
      a0 = mfma16f(e00, qb[0], a0);  a1 = mfma16f(e10, qb[0], a1);               \
      a0 = mfma16f(e01, qb[1], a0);  a1 = mfma16f(e11, qb[1], a1);               \
      a0 = mfma16f(e02, qb[2], a0);  a1 = mfma16f(e12, qb[2], a1);               \
    }                                                                            \
    const unsigned mw = bitm[4 * (TT) + sq];                                     \
    const unsigned tra = trBase + (unsigned)(bO * 2);                            \
    u16x4 ta0, tb0, ta1, tb1, ta2, tb2, ta3, tb3, ta4, tb4;                      \
    asm volatile("ds_read_b64_tr_b16 %0, %1"             : "=v"(ta0) : "v"(tra));\
    asm volatile("ds_read_b64_tr_b16 %0, %1 offset:3168" : "=v"(tb0) : "v"(tra));\
    asm volatile("ds_read_b64_tr_b16 %0, %1 offset:528"  : "=v"(ta1) : "v"(tra));\
    asm volatile("ds_read_b64_tr_b16 %0, %1 offset:3696" : "=v"(tb1) : "v"(tra));\
    asm volatile("ds_read_b64_tr_b16 %0, %1 offset:1056" : "=v"(ta2) : "v"(tra));\
    asm volatile("ds_read_b64_tr_b16 %0, %1 offset:4224" : "=v"(tb2) : "v"(tra));\
    asm volatile("ds_read_b64_tr_b16 %0, %1 offset:1584" : "=v"(ta3) : "v"(tra));\
    asm volatile("ds_read_b64_tr_b16 %0, %1 offset:4752" : "=v"(tb3) : "v"(tra));\
    asm volatile("ds_read_b64_tr_b16 %0, %1 offset:2112" : "=v"(ta4) : "v"(tra));\
    asm volatile("ds_read_b64_tr_b16 %0, %1 offset:5280" : "=v"(tb4) : "v"(tra));\
    float sv0[4], sv1[4];                                                        \
    _Pragma("unroll")                                                            \
    for (int rr = 0; rr < 4; ++rr) {                                             \
      sv0[rr] = ((mw >> (msh0 + rr)) & 1u) ? NEGINF : a0[rr];                    \
      sv1[rr] = ((mw >> (msh1 + rr)) & 1u) ? NEGINF : a1[rr];                    \
    }                                                                            \
    float tm = fmaxf(fmaxf(fmaxf(sv0[0], sv0[1]), fmaxf(sv0[2], sv0[3])),        \
                     fmaxf(fmaxf(sv1[0], sv1[1]), fmaxf(sv1[2], sv1[3])));       \
    tm = fmaxf(tm, __shfl_xor(tm, 16));                                          \
    tm = fmaxf(tm, __shfl_xor(tm, 32));                                          \
    const bool need = !__all(tm <= mr + 11.541560f);                             \
    if (need) {                                                                  \
      float mn = fmaxf(mr, tm);                                                  \
      float esc = E2(mr - mn);                                                   \
      lr *= esc; mr = mn;                                                        \
      float fr[4];                                                               \
      _Pragma("unroll")                                                          \
      for (int rr = 0; rr < 4; ++rr) fr[rr] = __shfl(esc, 4 * g + rr);           \
      _Pragma("unroll")                                                          \
      for (int n = 0; n < 5; ++n) {                                              \
        _Pragma("unroll")                                                        \
        for (int rr = 0; rr < 4; ++rr) ctx[n][rr] *= fr[rr];                     \
      }                                                                          \
    }                                                                            \
    float p0[4], p1[4];                                                          \
    _Pragma("unroll")                                                            \
    for (int rr = 0; rr < 4; ++rr) {                                             \
      p0[rr] = E2(sv0[rr] - mr);                                                 \
      p1[rr] = E2(sv1[rr] - mr);                                                 \
    }                                                                            \
    lr += ((p0[0] + p0[1]) + (p0[2] + p0[3])) + ((p1[0] + p1[1]) + (p1[2] + p1[3])); \
    union { unsigned uu[4]; f16x8 v; } PA;                                       \
    PA.uu[0] = pkh(p0[0], p0[1]); PA.uu[1] = pkh(p0[2], p0[3]);                  \
    PA.uu[2] = pkh(p1[0], p1[1]); PA.uu[3] = pkh(p1[2], p1[3]);                  \
    asm volatile("s_waitcnt lgkmcnt(0)" ::: "memory");                           \
    __builtin_amdgcn_sched_barrier(0);                                           \
    {                                                                            \
      union { u16 s[8]; f16x8 v; } B0, B1, B2, B3, B4;                           \
      _Pragma("unroll")                                                          \
      for (int j = 0; j < 4; ++j) {                                              \
        B0.s[j] = ta0[j]; B0.s[4 + j] = tb0[j];                                  \
        B1.s[j] = ta1[j]; B1.s[4 + j] = tb1[j];                                  \
        B2.s[j] = ta2[j]; B2.s[4 + j] = tb2[j];                                  \
        B3.s[j] = ta3[j]; B3.s[4 + j] = tb3[j];                                  \
        B4.s[j] = ta4[j]; B4.s[4 + j] = tb4[j];                                  \
      }                                                                          \
      ctx[0] = mfma16f(PA.v, B0.v, ctx[0]);                                      \
      ctx[1] = mfma16f(PA.v, B1.v, ctx[1]);                                      \
      ctx[2] = mfma16f(PA.v, B2.v, ctx[2]);                                      \
      ctx[3] = mfma16f(PA.v, B3.v, ctx[3]);                                      \
      ctx[4] = mfma16f(PA.v, B4.v, ctx[4]);                                      \
    }                                                                            \
  }

  for (int kp = 0; kp < 8; ++kp) {
    const int rb = (kp & 1) << 1;   // read bufs rb, rb+1
    const int wb = 2 - rb;          // write bufs wb, wb+1
    const int tp0 = 2 * kp, tp1 = 2 * kp + 1;
    const bool h0 = (tp0 + 2 < 16), h1 = (tp1 + 2 < 16);
    f32x4 r0, r1, r2, r3;
    if (h0 && ldr) LOAD_T(tp0 + 2);
    TILE_BODY(tp0, rb)
    if (h0 && ldr) STAGE_WRITE(wb);
    if (h1 && ldr) LOAD_T(tp1 + 2);
    TILE_BODY(tp1, rb + 1)
    if (h1 && ldr) STAGE_WRITE(wb + 1);
    __syncthreads();
  }

  // ---------- epilogue: reduce lr, merge 4 s-slices, normalize, write ----------
  lr += __shfl_xor(lr, 16);
  lr += __shfl_xor(lr, 32);
  if (g == 0) {
    mst[sq * 64 + 16 * pp + l15] = mr;
    lst[sq * 64 + 16 * pp + l15] = lr;
  }
  __syncthreads();
  float F;
  {
    const int pi = 16 * pp + l15;
    float M = fmaxf(fmaxf(mst[pi], mst[64 + pi]), fmaxf(mst[128 + pi], mst[192 + pi]));
    F = E2(mr - M);
  }
  float gg[4];
#pragma unroll
  for (int rr = 0; rr < 4; ++rr) gg[rr] = __shfl(F, 4 * g + rr);
  float* cacc = (float*)smem;  // [64][84] (buffers dead after final barrier)
  for (int qq = 0; qq < 4; ++qq) {
    if (sq == qq) {
#pragma unroll
      for (int n = 0; n < 5; ++n) {
#pragma unroll
        for (int rr = 0; rr < 4; ++rr) {
          const int row = 16 * pp + 4 * g + rr;
          const int col = 16 * n + l15;
          float v = ctx[n][rr] * gg[rr];
          if (qq == 0) cacc[row * 84 + col] = v;
          else         cacc[row * 84 + col] += v;
        }
      }
    }
    __syncthreads();
  }
  {
    const int op = tid >> 4, oc = tid & 15;
    float Mv = fmaxf(fmaxf(mst[op], mst[64 + op]), fmaxf(mst[128 + op], mst[192 + op]));
    float Lv = lst[op] * E2(mst[op] - Mv) + lst[64 + op] * E2(mst[64 + op] - Mv)
             + lst[128 + op] * E2(mst[128 + op] - Mv) + lst[192 + op] * E2(mst[192 + op] - Mv);
    float inv = 1.0f / Lv;
    float* orow = out + ((size_t)b * NP + op) * ND + oc * 5;
    const float* crow = cacc + op * 84 + oc * 5;
#pragma unroll
    for (int i = 0; i < 5; ++i) orow[i] = crow[i] * inv;
  }
}

extern "C" void kernel_launch(void* const* d_in, const int* in_sizes, int n_in,
                              void* d_out, int out_size, void* d_ws, size_t ws_size,
                              hipStream_t stream) {
  (void)in_sizes; (void)n_in; (void)out_size; (void)d_ws; (void)ws_size;
  const float* enc  = (const float*)d_in[0];
  const float* dec  = (const float*)d_in[1];
  const int*   mask = (const int*)d_in[2];
  const float* W    = (const float*)d_in[3];
  float* out = (float*)d_out;
  DecoderAttention_62989990363717_kernel<<<dim3(256), dim3(NTHREADS), 0, stream>>>(
      enc, dec, mask, W, out);
}

// Round 19
// 39.907 us; speedup vs baseline: 1.6187x; 1.0560x over previous
//
#include <hip/hip_runtime.h>

#define NB 256
#define NS 2048
#define NP 64
#define ND 80
#define STILE 128
#define NTILE 16            // NS/STILE
#define NTHREADS 1024
#define LOG2E 1.4426950408889634f

typedef __attribute__((ext_vector_type(4))) float f32x4;
typedef __attribute__((ext_vector_type(2))) __fp16 fp16x2;
typedef __attribute__((ext_vector_type(8))) _Float16 f16x8;
typedef __attribute__((ext_vector_type(4))) unsigned short u16x4;
typedef unsigned short u16;

// ---------------- LDS layout (bytes) ----------------
// ehP  u16[2][8][6][264] @ 0     (50688)  f16 enc, 16x16 [s][d] row-major regions;
//        region(q,n), q = s>>4 (8 quarters of 128-row tile), n = d-block (n=5 = K-pad,
//        zeroed once). Region stride 264 u16 (=528B); per-buf stride 12672 u16.
// mbias f32[2048]        @ 50688 (8192)   0.0 / -3e38 per s (mask preconverted)
// mst  f32[4][64] @ 58880 ; lst f32[4][64] @ 59904 ; modep @ 60928
// prologue overlay: W f32[80][84]@0 ; dec f32[64][84]@26880 ; qtmp f32[64][100]@0
// epilogue overlay: cacc f32[64][84]@0
#define SMEM_BYTES 60944

__device__ __forceinline__ float E2(float x) { return __builtin_amdgcn_exp2f(x); }
// f32x2 -> f16x2 (RTZ, single v_cvt_pkrtz_f16_f32)
__device__ __forceinline__ unsigned pkh(float lo, float hi) {
  union { fp16x2 h; unsigned u; } cv;
  cv.h = __builtin_amdgcn_cvt_pkrtz(lo, hi);
  return cv.u;
}

// 16x16 K=32 f16 MFMA. C/D: col=lane&15, row=4*(lane>>4)+r (dtype-independent).
// A and B share the (lane-group g, reg-slot j) -> k=8g+j map (verified R2-R15).
__device__ __forceinline__ f32x4 mfma16f(f16x8 a, f16x8 b, f32x4 c) {
  return __builtin_amdgcn_mfma_f32_16x16x32_f16(a, b, c, 0, 0, 0);
}

// R10/R14/R15 shape (best verified: 39.87us, no spill). R12/R13's shared-operand
// shape spilled (VGPR=64 + 10-19MB scratch) — do NOT double per-thread ctx/Q state.
// R16-R18 splits/quad-buffer all regressed — this is the consolidated best.
__global__ __launch_bounds__(NTHREADS, 4)
void DecoderAttention_62989990363717_kernel(const float* __restrict__ enc,
                                            const float* __restrict__ dec,
                                            const int* __restrict__ maskp,
                                            const float* __restrict__ W,
                                            float* __restrict__ out)
{
  __shared__ __align__(16) char smem[SMEM_BYTES];

  u16* ehP    = (u16*)smem;               // [2][12672]
  float* mbias = (float*)(smem + 50688);  // [2048]
  float* mst  = (float*)(smem + 58880);   // [4][64]
  float* lst  = (float*)(smem + 59904);   // [4][64]
  int* modep  = (int*)(smem + 60928);

  const int tid  = (int)threadIdx.x;
  const int lane = tid & 63;
  const int wv   = tid >> 6;    // 0..15
  const int pp   = wv & 3;      // p-block: rows [16*pp, 16*pp+16)
  const int sq   = wv >> 2;     // 32-row s-slice within tile: quarters {2sq, 2sq+1}
  const int l15  = lane & 15;
  const int g    = lane >> 4;
  const int b    = (int)blockIdx.x;

  const float* encB = enc + (size_t)b * NS * ND;
  const float* decB = dec + (size_t)b * NP * ND;

  // ---------- prologue: W, dec(scaled) -> LDS; mask->bias; Q ----------
  {
    float* Wl = (float*)smem;            // [80][84]
    float* dl = (float*)(smem + 26880);  // [64][84]
    for (int i = tid; i < 80 * 80; i += NTHREADS) Wl[(i / 80) * 84 + (i % 80)] = W[i];
    for (int i = tid; i < 64 * 80; i += NTHREADS)
      dl[(i / 80) * 84 + (i % 80)] = decB[i] * LOG2E;   // exp2-domain scores
    if (tid == 0) {
      const unsigned* mw = (const unsigned*)maskp;
      int ok = 1;
      for (int i = 0; i < 16; ++i) ok &= (mw[i] <= 1u);
      *modep = ok;   // 1 => int32 mask, 0 => int8 mask
    }
    __syncthreads();
    const int m32 = *modep;
    if (m32) {
      int v0 = maskp[(size_t)b * NS + tid];
      int v1 = maskp[(size_t)b * NS + tid + 1024];
      mbias[tid]        = v0 ? -3.0e38f : 0.0f;
      mbias[tid + 1024] = v1 ? -3.0e38f : 0.0f;
    } else if (tid < 512) {
      unsigned w = ((const unsigned*)maskp)[(size_t)b * (NS / 4) + tid];
      f32x4 bb;
      bb[0] = (w & 255u)         ? -3.0e38f : 0.0f;
      bb[1] = ((w >> 8) & 255u)  ? -3.0e38f : 0.0f;
      bb[2] = ((w >> 16) & 255u) ? -3.0e38f : 0.0f;
      bb[3] = (w >> 24)          ? -3.0e38f : 0.0f;
      *(f32x4*)&mbias[4 * tid] = bb;
    }
    // Q = dec @ W^T in fp32 (all 1024 threads: p = tid&63, e-range = 5*qw)
    float qa[5];
    const int qp = tid & 63, qw = tid >> 6;   // qw 0..15
#pragma unroll
    for (int j = 0; j < 5; ++j) qa[j] = 0.f;
    for (int kg = 0; kg < 20; ++kg) {
      f32x4 dv = *(const f32x4*)&dl[qp * 84 + kg * 4];
#pragma unroll
      for (int j = 0; j < 5; ++j) {
        f32x4 wv4 = *(const f32x4*)&Wl[(qw * 5 + j) * 84 + kg * 4];
        qa[j] = fmaf(dv.x, wv4.x, qa[j]);
        qa[j] = fmaf(dv.y, wv4.y, qa[j]);
        qa[j] = fmaf(dv.z, wv4.z, qa[j]);
        qa[j] = fmaf(dv.w, wv4.w, qa[j]);
      }
    }
    __syncthreads();            // Wl/dl reads done
    float* qtmp = (float*)smem; // [64][100], zeros at d=80..95
#pragma unroll
    for (int j = 0; j < 5; ++j) qtmp[qp * 100 + qw * 5 + j] = qa[j];
    if (qw == 15) {
#pragma unroll
      for (int z = 0; z < 16; ++z) qtmp[qp * 100 + 80 + z] = 0.f;
    }
    __syncthreads();
  }

  // ---------- Q fragments (persistent, single f16 RNE — no residual) ----------
  f16x8 qb[3];
  {
    const float* qtmp = (const float*)smem;
    const int prow = 16 * pp + l15;
#pragma unroll
    for (int kk = 0; kk < 3; ++kk) {
      const int d0 = kk * 32 + g * 8;
      f32x4 f0 = *(const f32x4*)&qtmp[prow * 100 + d0];
      f32x4 f1 = *(const f32x4*)&qtmp[prow * 100 + d0 + 4];
      union { _Float16 h[8]; f16x8 v; } H;
      H.h[0] = (_Float16)f0.x; H.h[1] = (_Float16)f0.y;
      H.h[2] = (_Float16)f0.z; H.h[3] = (_Float16)f0.w;
      H.h[4] = (_Float16)f1.x; H.h[5] = (_Float16)f1.y;
      H.h[6] = (_Float16)f1.z; H.h[7] = (_Float16)f1.w;
      qb[kk] = H.v;
    }
  }
  __syncthreads();   // qtmp dead; staging may overwrite

  // ---------- zero K-pad regions (n=5) once: both buffers, 8 quarters ----------
  if (tid < 256) {
    const int buf = tid >> 7, q = (tid >> 4) & 7, row = tid & 15;
    u16* p = ehP + buf * 12672 + (q * 6 + 5) * 264 + row * 16;
    *(uint4*)p = make_uint4(0u, 0u, 0u, 0u);
    *(uint4*)(p + 8) = make_uint4(0u, 0u, 0u, 0u);
  }

  // loader roles: tid<640 stage enc (5 threads/row, 16 f32 each, all-b128 writes)
  const bool ldr = (tid < 640);
  const int srow = tid / 5;                 // 0..127
  const int c    = tid - srow * 5;          // 0..4 (d-block of 16)
  u16* ePW = ehP + ((srow >> 4) * 6 + c) * 264 + (srow & 15) * 16;
  const float* gsrc = encB + srow * ND + 16 * c;

#define STAGE_WRITE(bi)                                                          \
  do {                                                                           \
    if (ldr) {                                                                   \
      unsigned hh[8];                                                            \
      hh[0] = pkh(r0.x, r0.y); hh[1] = pkh(r0.z, r0.w);                          \
      hh[2] = pkh(r1.x, r1.y); hh[3] = pkh(r1.z, r1.w);                          \
      hh[4] = pkh(r2.x, r2.y); hh[5] = pkh(r2.z, r2.w);                          \
      hh[6] = pkh(r3.x, r3.y); hh[7] = pkh(r3.z, r3.w);                          \
      u16* a_ = ePW + (bi) * 12672;                                              \
      *(uint4*)a_       = make_uint4(hh[0], hh[1], hh[2], hh[3]);                \
      *(uint4*)(a_ + 8) = make_uint4(hh[4], hh[5], hh[6], hh[7]);                \
    }                                                                            \
  } while (0)

  // ---------- stage tile 0 ----------
  {
    f32x4 r0, r1, r2, r3;
    if (ldr) {
      r0 = *(const f32x4*)gsrc;       r1 = *(const f32x4*)(gsrc + 4);
      r2 = *(const f32x4*)(gsrc + 8); r3 = *(const f32x4*)(gsrc + 12);
    }
    STAGE_WRITE(0);
    __syncthreads();
  }

  // ---------- main loop ----------
  f32x4 ctx[5];
#pragma unroll
  for (int n = 0; n < 5; ++n) ctx[n] = (f32x4){0.f, 0.f, 0.f, 0.f};
  // mr init -1e30 (NOT -3e38): masked rows give sv=-3e38 -> E2(sv-mr)=0 even
  // before any real max is seen (fully-masked-first-tile safety).
  float mr = -1.0e30f, lr = 0.f;   // lr: per-lane partial (reduced in epilogue)

  // QK A-frag base (u16 idx): region(2sq+blk, (g>>1)+2kk) + 16*l15 + 8*(g&1)
  //   -> element d = 32kk + 8g + j  (matches qb slot map)
  const int qkOff = (2 * sq) * 1584 + (g >> 1) * 264 + 16 * l15 + 8 * (g & 1);
  // PV tr-read base (bytes): region(2sq, n) + 8*lane; blk1 = +3168B, n-step = 528B
  const unsigned trBase = (unsigned)(uintptr_t)ehP + (unsigned)(sq * 6336 + 8 * lane);

  for (int tt = 0; tt < NTILE; ++tt) {
    const int cur = tt & 1, nxt = cur ^ 1;
    const bool hn = (tt + 1 < NTILE);
    f32x4 r0, r1, r2, r3;
    if (hn && ldr) {   // issue next-tile loads early (consumed at STAGE_WRITE)
      const float* src = gsrc + (size_t)(tt + 1) * STILE * ND;
      r0 = *(const f32x4*)src;       r1 = *(const f32x4*)(src + 4);
      r2 = *(const f32x4*)(src + 8); r3 = *(const f32x4*)(src + 12);
    }

    // ---- QK^T (swapped): two 16-row blocks, K=96, single-f16 Q ----
    f32x4 a0 = (f32x4){0.f, 0.f, 0.f, 0.f}, a1 = (f32x4){0.f, 0.f, 0.f, 0.f};
    {
      const u16* baseH0 = ehP + cur * 12672 + qkOff;
      const u16* baseH1 = baseH0 + 1584;
      f16x8 e0[3], e1[3];
#pragma unroll
      for (int kk = 0; kk < 3; ++kk) {
        e0[kk] = *(const f16x8*)(const void*)(baseH0 + kk * 528);
        e1[kk] = *(const f16x8*)(const void*)(baseH1 + kk * 528);
      }
#pragma unroll
      for (int kk = 0; kk < 3; ++kk) {
        a0 = mfma16f(e0[kk], qb[kk], a0);
        a1 = mfma16f(e1[kk], qb[kk], a1);
      }
    }

    // ---- hoist bias loads (LDS) before the tr-read burst ----
    const int mb0 = tt * 128 + 32 * sq + 4 * g;
    f32x4 bias0 = *(const f32x4*)&mbias[mb0];
    f32x4 bias1 = *(const f32x4*)&mbias[mb0 + 16];

    // ---- issue ALL 10 PV tr-reads NOW; latency hides under softmax VALU ----
    const unsigned tra = trBase + (unsigned)(cur * 25344);
    u16x4 ta0, tb0, ta1, tb1, ta2, tb2, ta3, tb3, ta4, tb4;
    asm volatile("ds_read_b64_tr_b16 %0, %1"             : "=v"(ta0) : "v"(tra));
    asm volatile("ds_read_b64_tr_b16 %0, %1 offset:3168" : "=v"(tb0) : "v"(tra));
    asm volatile("ds_read_b64_tr_b16 %0, %1 offset:528"  : "=v"(ta1) : "v"(tra));
    asm volatile("ds_read_b64_tr_b16 %0, %1 offset:3696" : "=v"(tb1) : "v"(tra));
    asm volatile("ds_read_b64_tr_b16 %0, %1 offset:1056" : "=v"(ta2) : "v"(tra));
    asm volatile("ds_read_b64_tr_b16 %0, %1 offset:4224" : "=v"(tb2) : "v"(tra));
    asm volatile("ds_read_b64_tr_b16 %0, %1 offset:1584" : "=v"(ta3) : "v"(tra));
    asm volatile("ds_read_b64_tr_b16 %0, %1 offset:4752" : "=v"(tb3) : "v"(tra));
    asm volatile("ds_read_b64_tr_b16 %0, %1 offset:2112" : "=v"(ta4) : "v"(tra));
    asm volatile("ds_read_b64_tr_b16 %0, %1 offset:5280" : "=v"(tb4) : "v"(tra));

    // ---- masked online softmax over 32 rows (exp2 domain), defer-max ----
    float sv0[4], sv1[4];
#pragma unroll
    for (int rr = 0; rr < 4; ++rr) {
      sv0[rr] = a0[rr] + bias0[rr];
      sv1[rr] = a1[rr] + bias1[rr];
    }
    float tm = fmaxf(fmaxf(fmaxf(sv0[0], sv0[1]), fmaxf(sv0[2], sv0[3])),
                     fmaxf(fmaxf(sv1[0], sv1[1]), fmaxf(sv1[2], sv1[3])));
    tm = fmaxf(tm, __shfl_xor(tm, 16));
    tm = fmaxf(tm, __shfl_xor(tm, 32));
    const bool need = !__all(tm <= mr + 11.541560f);   // 8 * log2(e)
    if (need) {
      float mn = fmaxf(mr, tm);
      float esc = E2(mr - mn);
      lr *= esc; mr = mn;
      float fr[4];
#pragma unroll
      for (int rr = 0; rr < 4; ++rr) fr[rr] = __shfl(esc, 4 * g + rr);
#pragma unroll
      for (int n = 0; n < 5; ++n) {
#pragma unroll
        for (int rr = 0; rr < 4; ++rr) ctx[n][rr] *= fr[rr];
      }
    }
    float p0[4], p1[4];
#pragma unroll
    for (int rr = 0; rr < 4; ++rr) {
      p0[rr] = E2(sv0[rr] - mr);
      p1[rr] = E2(sv1[rr] - mr);
    }
    lr += ((p0[0] + p0[1]) + (p0[2] + p0[3])) + ((p1[0] + p1[1]) + (p1[2] + p1[3]));

    // ---- PV: full-K=32 MFMA. A slots: j=0..3 <- blk0 rows 4g+j,
    //      j=4..7 <- blk1 rows 4g+j. B: tr-read(blk, n) delivers
    //      E_blk[4g+j][16n+l15] into slots 4*blk+j — same k->s map. ----
    union { unsigned uu[4]; f16x8 v; } PA;
    PA.uu[0] = pkh(p0[0], p0[1]); PA.uu[1] = pkh(p0[2], p0[3]);
    PA.uu[2] = pkh(p1[0], p1[1]); PA.uu[3] = pkh(p1[2], p1[3]);
    asm volatile("s_waitcnt lgkmcnt(0)" ::: "memory");
    __builtin_amdgcn_sched_barrier(0);
    {
      union { u16 s[8]; f16x8 v; } B0, B1, B2, B3, B4;
#pragma unroll
      for (int j = 0; j < 4; ++j) {
        B0.s[j] = ta0[j]; B0.s[4 + j] = tb0[j];
        B1.s[j] = ta1[j]; B1.s[4 + j] = tb1[j];
        B2.s[j] = ta2[j]; B2.s[4 + j] = tb2[j];
        B3.s[j] = ta3[j]; B3.s[4 + j] = tb3[j];
        B4.s[j] = ta4[j]; B4.s[4 + j] = tb4[j];
      }
      ctx[0] = mfma16f(PA.v, B0.v, ctx[0]);
      ctx[1] = mfma16f(PA.v, B1.v, ctx[1]);
      ctx[2] = mfma16f(PA.v, B2.v, ctx[2]);
      ctx[3] = mfma16f(PA.v, B3.v, ctx[3]);
      ctx[4] = mfma16f(PA.v, B4.v, ctx[4]);
    }

    if (hn) { STAGE_WRITE(nxt); }
    __syncthreads();
  }

  // ---------- epilogue: reduce lr, merge 4 s-slices, normalize, write ----------
  lr += __shfl_xor(lr, 16);
  lr += __shfl_xor(lr, 32);
  if (g == 0) {
    mst[sq * 64 + 16 * pp + l15] = mr;
    lst[sq * 64 + 16 * pp + l15] = lr;
  }
  __syncthreads();
  float F;
  {
    const int pi = 16 * pp + l15;
    float M = fmaxf(fmaxf(mst[pi], mst[64 + pi]), fmaxf(mst[128 + pi], mst[192 + pi]));
    F = E2(mr - M);
  }
  float gg[4];
#pragma unroll
  for (int rr = 0; rr < 4; ++rr) gg[rr] = __shfl(F, 4 * g + rr);
  float* cacc = (float*)smem;  // [64][84]
  for (int qq = 0; qq < 4; ++qq) {
    if (sq == qq) {
#pragma unroll
      for (int n = 0; n < 5; ++n) {
#pragma unroll
        for (int rr = 0; rr < 4; ++rr) {
          const int row = 16 * pp + 4 * g + rr;
          const int col = 16 * n + l15;
          float v = ctx[n][rr] * gg[rr];
          if (qq == 0) cacc[row * 84 + col] = v;
          else         cacc[row * 84 + col] += v;
        }
      }
    }
    __syncthreads();
  }
  {
    const int op = tid >> 4, oc = tid & 15;
    float Mv = fmaxf(fmaxf(mst[op], mst[64 + op]), fmaxf(mst[128 + op], mst[192 + op]));
    float Lv = lst[op] * E2(mst[op] - Mv) + lst[64 + op] * E2(mst[64 + op] - Mv)
             + lst[128 + op] * E2(mst[128 + op] - Mv) + lst[192 + op] * E2(mst[192 + op] - Mv);
    float inv = 1.0f / Lv;
    float* orow = out + ((size_t)b * NP + op) * ND + oc * 5;
    const float* crow = cacc + op * 84 + oc * 5;
#pragma unroll
    for (int i = 0; i < 5; ++i) orow[i] = crow[i] * inv;
  }
}

extern "C" void kernel_launch(void* const* d_in, const int* in_sizes, int n_in,
                              void* d_out, int out_size, void* d_ws, size_t ws_size,
                              hipStream_t stream) {
  (void)in_sizes; (void)n_in; (void)out_size; (void)d_ws; (void)ws_size;
  const float* enc  = (const float*)d_in[0];
  const float* dec  = (const float*)d_in[1];
  const int*   mask = (const int*)d_in[2];
  const float* W    = (const float*)d_in[3];
  float* out = (float*)d_out;
  DecoderAttention_62989990363717_kernel<<<dim3(NB), dim3(NTHREADS), 0, stream>>>(
      enc, dec, mask, W, out);
}